// Round 7
// baseline (4023.437 us; speedup 1.0000x reference)
//
#include <hip/hip_runtime.h>
#include <cstddef>

#define NN 256      // N
#define PP 256      // P
#define BB 128      // B
#define KK 4        // K
#define NSYS 512    // K*B
#define PW 32       // panel width
#define NPAN (NN/PW)
#define PACKSZ 65536   // floats per system: Dpack 8192 + Lpack 28672 + Upack 28672

__device__ __forceinline__ float sigmoidf_(float x){ return 1.0f/(1.0f+expf(-x)); }
__device__ __forceinline__ int loff_(int J){ return 8192 + 32*(224*J - 16*J*(J-1)); }
__device__ __forceinline__ int uoff_(int J){ return 36864 + 512*J*(J-1); }

// ---------------------------------------------------------------------------
// Kernel 1: build Cm (A) and rowsum(Cm) for systems [s0,s0+cs)
// ---------------------------------------------------------------------------
__global__ __launch_bounds__(256) void build_kernel(
    const float* __restrict__ C, const float* __restrict__ rm,
    const float* __restrict__ epsp, const int* __restrict__ bad,
    float* __restrict__ A, float* __restrict__ rowsum, int s0)
{
  const int si = blockIdx.x;
  const int ls = si >> 8;
  const int i  = si & 255;
  const int s  = s0 + ls;
  const int k  = s >> 7;
  const int b  = s & 127;
  const int j  = threadIdx.x;

  const float sk = sigmoidf_(rm[k]);
  const float ek = sigmoidf_(epsp[k]);
  const bool bad_i = bad[b*NN + i] != 0;
  const bool bad_j = bad[b*NN + j] != 0;

  float c  = C[((size_t)b*NN + i)*(NN+PP) + j];
  float x  = sk * c;
  float cf = (1.0f + x) * expf(-x);
  if (i == j) cf += ek;              // diag: C[i][i]==0 -> cf==1, add eps
  float keep = (bad_i == bad_j) ? 1.0f : 0.0f;
  float a = cf * keep;
  A[((size_t)ls*NN + i)*NN + j] = a;

  __shared__ float red[256];
  red[j] = a; __syncthreads();
  #pragma unroll
  for (int off = 128; off > 0; off >>= 1){
    if (j < off) red[j] += red[j + off];
    __syncthreads();
  }
  if (j == 0) rowsum[ls*NN + i] = red[0];
}

// ---------------------------------------------------------------------------
// Kernel 2: swap-free blocked LU with partial pivoting ("pick-order").
// (unchanged from round 6 — known good)
// ---------------------------------------------------------------------------
__global__ __launch_bounds__(512, 4) void lu_kernel(
    float* __restrict__ Aall, int* __restrict__ permAll)
{
  __shared__ float panel[NN][PW+1];
  __shared__ float linv[PW][PW+1];
  __shared__ float uinv[PW][PW+1];
  __shared__ float urow[PW][NN-PW];
  __shared__ float redv[2][8];
  __shared__ int   redi[2][8];
  __shared__ int   pivseq[NN];
  __shared__ int   actlist[NN];
  __shared__ unsigned char pickedsh[NN];
  __shared__ int   nact;

  const int ls = blockIdx.x;
  float* __restrict__ A = Aall + (size_t)ls*NN*NN;
  const int t = threadIdx.x;
  const int lane = t & 63, wid = t >> 6;
  bool picked = false;
  if (t < NN) pickedsh[t] = 0;

  for (int I = 0; I < NPAN; ++I){
    const int col0 = I*PW;
    const int W = NN - col0 - PW;
    if (t == 0) nact = 0;
    __syncthreads();

    for (int e = t; e < NN*PW; e += 512){
      int r = e >> 5, c = e & 31;
      panel[r][c] = A[(size_t)r*NN + col0 + c];
    }
    __syncthreads();

    {
      float v = -1.0f; int vi = 0;
      if (t < NN && !picked){ v = fabsf(panel[t][0]); vi = t; }
      #pragma unroll
      for (int off = 32; off > 0; off >>= 1){
        float ov = __shfl_down(v, off); int oi = __shfl_down(vi, off);
        if (ov > v){ v = ov; vi = oi; }
      }
      if (lane == 0){ redv[0][wid] = v; redi[0][wid] = vi; }
    }
    __syncthreads();

    for (int c = 0; c < PW; ++c){
      const int par = c & 1;
      float bv = redv[par][0]; int p = redi[par][0];
      #pragma unroll
      for (int w = 1; w < 8; ++w)
        if (redv[par][w] > bv){ bv = redv[par][w]; p = redi[par][w]; }
      if (t == p){ picked = true; pickedsh[t] = 1; pivseq[col0+c] = t; }

      float nv = -1.0f; int ni = t;
      if (t < NN && !picked){
        const float rdia = 1.0f / panel[p][c];
        float m = panel[t][c] * rdia;
        panel[t][c] = m;
        float nxt = -1.0f;
        #pragma unroll
        for (int j = 0; j < PW; ++j){
          if (j > c){
            float u = panel[t][j] - m * panel[p][j];
            panel[t][j] = u;
            if (j == c+1) nxt = fabsf(u);
          }
        }
        nv = nxt;
      }
      #pragma unroll
      for (int off = 32; off > 0; off >>= 1){
        float ov = __shfl_down(nv, off); int oi = __shfl_down(ni, off);
        if (ov > nv){ nv = ov; ni = oi; }
      }
      if (lane == 0){ redv[par^1][wid] = nv; redi[par^1][wid] = ni; }
      __syncthreads();
    }

    if (t >= 256){
      const int jj = t - 256;
      if (jj < W){
        const int j = col0 + PW + jj;
        float u[PW];
        #pragma unroll
        for (int c = 0; c < PW; ++c) u[c] = A[(size_t)pivseq[col0+c]*NN + j];
        #pragma unroll
        for (int c = 0; c < PW; ++c){
          const int pc = pivseq[col0+c];
          float sv = u[c];
          #pragma unroll
          for (int k2 = 0; k2 < PW; ++k2)
            if (k2 < c) sv -= panel[pc][k2] * u[k2];
          u[c] = sv;
          urow[c][jj] = sv;
          A[(size_t)pc*NN + j] = sv;
        }
      }
    } else if (t < PW){
      const int cth = t;
      for (int r = cth; r < PW; ++r){
        float sv = (r == cth) ? 1.0f : 0.0f;
        const int pr = pivseq[col0+r];
        for (int k2 = cth; k2 < r; ++k2) sv -= panel[pr][k2] * linv[k2][cth];
        linv[r][cth] = sv;
      }
    } else if (t >= 64 && t < 64+PW){
      const int cth = t - 64;
      for (int r = cth; r >= 0; --r){
        float sv = (r == cth) ? 1.0f : 0.0f;
        const int pr = pivseq[col0+r];
        for (int k2 = r+1; k2 <= cth; ++k2) sv -= panel[pr][k2] * uinv[k2][cth];
        uinv[r][cth] = sv / panel[pr][r];
      }
    } else if (t >= 128 && t < 192){
      #pragma unroll
      for (int q = 0; q < 4; ++q){
        int r = (t-128)*4 + q;
        if (!pickedsh[r]){ int pos = atomicAdd(&nact, 1); actlist[pos] = r; }
      }
    }
    __syncthreads();

    for (int e = t; e < PW*PW; e += 512){
      int r = e >> 5, c2 = e & 31;
      A[(size_t)pivseq[col0+r]*NN + col0 + c2] = (r > c2) ? linv[r][c2] : uinv[r][c2];
    }
    for (int e = t; e < NN*PW; e += 512){
      int r = e >> 5, c2 = e & 31;
      if (!pickedsh[r]) A[(size_t)r*NN + col0 + c2] = panel[r][c2];
    }

    if (W > 0){
      for (int i0 = wid*2; i0 < W; i0 += 16){
        const bool two = (i0+1 < W);
        const int r0 = actlist[i0];
        const int r1 = actlist[two ? i0+1 : i0];
        float* R0 = A + (size_t)r0*NN + col0 + PW;
        float* R1 = A + (size_t)r1*NN + col0 + PW;
        for (int jb = 0; jb < W; jb += 64){
          const int j2 = jb + lane;
          const bool ok = (j2 < W);
          const int j2c = ok ? j2 : 0;
          float a0 = R0[j2c], a1 = R1[j2c];
          #pragma unroll
          for (int c = 0; c < PW; ++c){
            float uu = urow[c][j2c];
            a0 -= panel[r0][c]*uu;
            a1 -= panel[r1][c]*uu;
          }
          if (ok){ R0[j2] = a0; if (two) R1[j2] = a1; }
        }
      }
    }
  }
  __syncthreads();
  if (t < NN) permAll[ls*NN + t] = pivseq[t];
}

// ---------------------------------------------------------------------------
// Kernel 2b: repack A (physical rows) into solve-order streams.
//   Dpack [0,8192):      8 diag blocks (packed Linv/Uinv), logical order
//   Lpack [8192,36864):  per fwd panel J: rows j0+32..255 x 32 cols, row-major
//   Upack [36864,65536): per bwd panel J: rows 0..j0-1    x 32 cols, row-major
// ---------------------------------------------------------------------------
__global__ __launch_bounds__(512) void repack_kernel(
    const float* __restrict__ Aall, const int* __restrict__ permAll,
    float* __restrict__ Pack)
{
  __shared__ int perm[NN];
  const int ls = blockIdx.x;
  const float* __restrict__ A = Aall + (size_t)ls*NN*NN;
  float* __restrict__ Pk = Pack + (size_t)ls*PACKSZ;
  const int t = threadIdx.x;
  if (t < NN) perm[t] = permAll[ls*NN + t];
  __syncthreads();

  for (int e = t; e < 8192; e += 512){
    int J = e >> 10, r = (e >> 5) & 31, c = e & 31;
    Pk[e] = A[(size_t)perm[(J<<5)+r]*NN + (J<<5) + c];
  }
  for (int J = 0; J < 7; ++J){
    const int rows = 224 - 32*J;
    const int base = loff_(J);
    const int j0 = 32*J;
    for (int e = t; e < rows*32; e += 512){
      int lr = e >> 5, c = e & 31;
      Pk[base + e] = A[(size_t)perm[j0+32+lr]*NN + j0 + c];
    }
  }
  for (int J = 1; J < 8; ++J){
    const int base = uoff_(J);
    const int j0 = 32*J;
    for (int e = t; e < j0*32; e += 512){
      int i = e >> 5, c = e & 31;
      Pk[base + e] = A[(size_t)perm[i]*NN + j0 + c];
    }
  }
}

// ---------------------------------------------------------------------------
// Kernel 3: blocked triangular solves + epilogue, reading packed streams.
// grid = cs*4 blocks: ls = blockIdx>>2, chunk = (blockIdx&3)*64.
// ---------------------------------------------------------------------------
__global__ __launch_bounds__(512, 4) void solve_epi_kernel(
    const float* __restrict__ Pack, const int* __restrict__ permAll,
    const float* __restrict__ rowsum,
    const float* __restrict__ C, const float* __restrict__ val,
    const int* __restrict__ bad, const float* __restrict__ rm,
    float* __restrict__ out, int s0)
{
  __shared__ float tile[NN][64];      // 64 KiB
  __shared__ float dblk[PW][PW+1];
  __shared__ float ep[4][8][64];
  __shared__ int   perm[NN];

  const int ls = blockIdx.x >> 2;
  const int c0 = (blockIdx.x & 3) * 64;
  const int s  = s0 + ls;
  const int k  = s >> 7, b = s & 127;
  const float* __restrict__ Pk = Pack + (size_t)ls*PACKSZ;
  const float* __restrict__ rs = rowsum + ls*NN;
  const int t = threadIdx.x;
  const int lane = t & 63, wid = t >> 6;
  const float sk = sigmoidf_(rm[k]);

  if (t < NN) perm[t] = permAll[ls*NN + t];
  __syncthreads();

  // ---- build permuted RHS chunk on the fly ----
  for (int e = t; e < NN*64; e += 512){
    int i = e >> 6, c = e & 63;
    int pi = perm[i];
    float cb = C[((size_t)b*NN + pi)*(NN+PP) + NN + c0 + c];
    float xb = sk * cb;
    float bf = (1.0f + xb) * expf(-xb);
    if (bad[b*NN + pi]) bf = 0.0f;
    tile[i][c] = bf;
  }
  __syncthreads();

  // ---- forward: y = Linv-chain applied to Pb ----
  for (int J = 0; J < NPAN; ++J){
    const int j0 = J*PW;
    for (int e = t; e < PW*PW; e += 512){
      dblk[e >> 5][e & 31] = Pk[(J << 10) + e];
    }
    __syncthreads();
    const int r0 = wid*4;
    float y0 = tile[j0+r0+0][lane];
    float y1 = tile[j0+r0+1][lane];
    float y2 = tile[j0+r0+2][lane];
    float y3 = tile[j0+r0+3][lane];
    for (int kk = 0; kk < r0; ++kk){
      float xk = tile[j0+kk][lane];
      y0 += dblk[r0+0][kk]*xk;
      y1 += dblk[r0+1][kk]*xk;
      y2 += dblk[r0+2][kk]*xk;
      y3 += dblk[r0+3][kk]*xk;
    }
    {
      float x0 = tile[j0+r0][lane], x1 = tile[j0+r0+1][lane], x2 = tile[j0+r0+2][lane];
      y1 += dblk[r0+1][r0]*x0;
      y2 += dblk[r0+2][r0]*x0 + dblk[r0+2][r0+1]*x1;
      y3 += dblk[r0+3][r0]*x0 + dblk[r0+3][r0+1]*x1 + dblk[r0+3][r0+2]*x2;
    }
    __syncthreads();
    tile[j0+r0+0][lane]=y0; tile[j0+r0+1][lane]=y1;
    tile[j0+r0+2][lane]=y2; tile[j0+r0+3][lane]=y3;
    __syncthreads();
    if (j0 + PW < NN){
      float x[PW];
      #pragma unroll
      for (int kk = 0; kk < PW; ++kk) x[kk] = tile[j0+kk][lane];
      const float* __restrict__ Lp = Pk + loff_(J);
      const int nrows = NN - j0 - PW;
      for (int lr = wid*2; lr < nrows; lr += 16){
        const float4* __restrict__ Ar0 = (const float4*)(Lp + (size_t)lr*32);
        const float4* __restrict__ Ar1 = (const float4*)(Lp + (size_t)(lr+1)*32);
        float acc0 = tile[j0+PW+lr  ][lane];
        float acc1 = tile[j0+PW+lr+1][lane];
        #pragma unroll
        for (int q = 0; q < 8; ++q){
          float4 a4 = Ar0[q], b4 = Ar1[q];
          acc0 -= a4.x*x[q*4+0] + a4.y*x[q*4+1] + a4.z*x[q*4+2] + a4.w*x[q*4+3];
          acc1 -= b4.x*x[q*4+0] + b4.y*x[q*4+1] + b4.z*x[q*4+2] + b4.w*x[q*4+3];
        }
        tile[j0+PW+lr  ][lane] = acc0;
        tile[j0+PW+lr+1][lane] = acc1;
      }
    }
    __syncthreads();
  }

  // ---- backward: d = Uinv-chain applied to y ----
  for (int J = NPAN-1; J >= 0; --J){
    const int j0 = J*PW;
    for (int e = t; e < PW*PW; e += 512){
      dblk[e >> 5][e & 31] = Pk[(J << 10) + e];
    }
    __syncthreads();
    const int r0 = wid*4;
    float y0=0.f, y1=0.f, y2=0.f, y3=0.f;
    for (int kk = r0+4; kk < PW; ++kk){
      float xk = tile[j0+kk][lane];
      y0 += dblk[r0+0][kk]*xk;
      y1 += dblk[r0+1][kk]*xk;
      y2 += dblk[r0+2][kk]*xk;
      y3 += dblk[r0+3][kk]*xk;
    }
    {
      float x0 = tile[j0+r0][lane], x1 = tile[j0+r0+1][lane];
      float x2 = tile[j0+r0+2][lane], x3 = tile[j0+r0+3][lane];
      y0 += dblk[r0][r0]*x0 + dblk[r0][r0+1]*x1 + dblk[r0][r0+2]*x2 + dblk[r0][r0+3]*x3;
      y1 += dblk[r0+1][r0+1]*x1 + dblk[r0+1][r0+2]*x2 + dblk[r0+1][r0+3]*x3;
      y2 += dblk[r0+2][r0+2]*x2 + dblk[r0+2][r0+3]*x3;
      y3 += dblk[r0+3][r0+3]*x3;
    }
    __syncthreads();
    tile[j0+r0+0][lane]=y0; tile[j0+r0+1][lane]=y1;
    tile[j0+r0+2][lane]=y2; tile[j0+r0+3][lane]=y3;
    __syncthreads();
    if (j0 > 0){
      float x[PW];
      #pragma unroll
      for (int kk = 0; kk < PW; ++kk) x[kk] = tile[j0+kk][lane];
      const float* __restrict__ Up = Pk + uoff_(J);
      for (int i = wid*2; i < j0; i += 16){
        const float4* __restrict__ Ar0 = (const float4*)(Up + (size_t)i*32);
        const float4* __restrict__ Ar1 = (const float4*)(Up + (size_t)(i+1)*32);
        float acc0 = tile[i  ][lane];
        float acc1 = tile[i+1][lane];
        #pragma unroll
        for (int q = 0; q < 8; ++q){
          float4 a4 = Ar0[q], b4 = Ar1[q];
          acc0 -= a4.x*x[q*4+0] + a4.y*x[q*4+1] + a4.z*x[q*4+2] + a4.w*x[q*4+3];
          acc1 -= b4.x*x[q*4+0] + b4.y*x[q*4+1] + b4.z*x[q*4+2] + b4.w*x[q*4+3];
        }
        tile[i  ][lane] = acc0;
        tile[i+1][lane] = acc1;
      }
    }
    __syncthreads();
  }

  // ---- epilogue: 8-wave partial column reductions + combine ----
  {
    const int p = c0 + lane;
    float sdv=0.f, sabs=0.f, s1v=0.f, s1=0.f;
    for (int j = wid*32; j < wid*32 + 32; ++j){
      float d = tile[j][lane];
      float v = val[(b*NN + j)*KK + k];
      if (v != v) v = 0.0f;
      float cb = C[((size_t)b*NN + j)*(NN+PP) + NN + p];
      float xb = sk*cb;
      float bo = (1.0f+xb)*expf(-xb);
      if (bad[b*NN + j]) bo = 0.0f;
      float d1 = bo / rs[j];
      sdv += d*v; sabs += fabsf(d); s1v += d1*v; s1 += d1;
    }
    ep[0][wid][lane]=sdv; ep[1][wid][lane]=sabs; ep[2][wid][lane]=s1v; ep[3][wid][lane]=s1;
  }
  __syncthreads();
  if (t < 64){
    float sdv=0.f, sabs=0.f, s1v=0.f, s1=0.f;
    #pragma unroll
    for (int w = 0; w < 8; ++w){
      sdv += ep[0][w][lane]; sabs += ep[1][w][lane];
      s1v += ep[2][w][lane]; s1  += ep[3][w][lane];
    }
    float wg    = fminf(fmaxf((sabs - 1.0f)*2.0f, 0.0f), 1.0f);
    float denom = fmaxf(s1, 1.0f);
    out[((size_t)b*PP + c0 + lane)*KK + k] = (1.0f - wg)*sdv + (wg/denom)*s1v;
  }
}

// ---------------------------------------------------------------------------
extern "C" void kernel_launch(void* const* d_in, const int* in_sizes, int n_in,
                              void* d_out, int out_size, void* d_ws, size_t ws_size,
                              hipStream_t stream)
{
  (void)in_sizes; (void)n_in; (void)out_size;
  const float* C    = (const float*)d_in[0];
  const float* val  = (const float*)d_in[1];
  const float* rm   = (const float*)d_in[2];
  const float* epsp = (const float*)d_in[3];
  const int*   bad  = (const int*)d_in[4];
  float* out = (float*)d_out;

  // per-system: A (64K f32) + Pack (64K f32) + rowsum (NN) + perm (NN)
  const size_t per_sys = (size_t)NN*NN*4 + (size_t)PACKSZ*4 + (size_t)NN*4 + (size_t)NN*4;
  int chunk = (int)(ws_size / per_sys);
  if (chunk < 1)    chunk = 1;
  if (chunk > NSYS) chunk = NSYS;

  float* ws     = (float*)d_ws;
  float* A      = ws;
  float* Pack   = A + (size_t)chunk*NN*NN;
  float* rowsum = Pack + (size_t)chunk*PACKSZ;
  int*   perm   = (int*)(rowsum + (size_t)chunk*NN);

  for (int s0 = 0; s0 < NSYS; s0 += chunk){
    int cs = (NSYS - s0 < chunk) ? (NSYS - s0) : chunk;
    build_kernel<<<cs*NN, 256, 0, stream>>>(C, rm, epsp, bad, A, rowsum, s0);
    lu_kernel<<<cs, 512, 0, stream>>>(A, perm);
    repack_kernel<<<cs, 512, 0, stream>>>(A, perm, Pack);
    solve_epi_kernel<<<cs*4, 512, 0, stream>>>(Pack, perm, rowsum, C, val, bad, rm, out, s0);
  }
}

// Round 8
// 1779.531 us; speedup vs baseline: 2.2610x; 2.2610x over previous
//
#include <hip/hip_runtime.h>
#include <cstddef>

#define NN 256      // N
#define PP 256      // P
#define BB 128      // B
#define KK 4        // K
#define NSYS 512    // K*B
#define PW 32       // panel width
#define NPAN (NN/PW)

__device__ __forceinline__ float sigmoidf_(float x){ return 1.0f/(1.0f+expf(-x)); }

// ---------------------------------------------------------------------------
// Kernel 1: build Cm (A) and rowsum(Cm) for systems [s0,s0+cs)
// ---------------------------------------------------------------------------
__global__ __launch_bounds__(256) void build_kernel(
    const float* __restrict__ C, const float* __restrict__ rm,
    const float* __restrict__ epsp, const int* __restrict__ bad,
    float* __restrict__ A, float* __restrict__ rowsum, int s0)
{
  const int si = blockIdx.x;
  const int ls = si >> 8;
  const int i  = si & 255;
  const int s  = s0 + ls;
  const int k  = s >> 7;
  const int b  = s & 127;
  const int j  = threadIdx.x;

  const float sk = sigmoidf_(rm[k]);
  const float ek = sigmoidf_(epsp[k]);
  const bool bad_i = bad[b*NN + i] != 0;
  const bool bad_j = bad[b*NN + j] != 0;

  float c  = C[((size_t)b*NN + i)*(NN+PP) + j];
  float x  = sk * c;
  float cf = (1.0f + x) * expf(-x);
  if (i == j) cf += ek;              // diag: C[i][i]==0 -> cf==1, add eps
  float keep = (bad_i == bad_j) ? 1.0f : 0.0f;
  float a = cf * keep;
  A[((size_t)ls*NN + i)*NN + j] = a;

  __shared__ float red[256];
  red[j] = a; __syncthreads();
  #pragma unroll
  for (int off = 128; off > 0; off >>= 1){
    if (j < off) red[j] += red[j + off];
    __syncthreads();
  }
  if (j == 0) rowsum[ls*NN + i] = red[0];
}

// ---------------------------------------------------------------------------
// Kernel 2: swap-free blocked LU with partial pivoting ("pick-order").
// Rows never move: thread t owns physical row t; pivot order -> pivseq.
// Trailing update float4-ized (b128 LDS reads, float4 global RMW).
// ---------------------------------------------------------------------------
__global__ __launch_bounds__(512, 4) void lu_kernel(
    float* __restrict__ Aall, int* __restrict__ permAll)
{
  __shared__ float panel[NN][PW+1];
  __shared__ float linv[PW][PW+1];
  __shared__ float uinv[PW][PW+1];
  __shared__ float urow[PW][NN-PW];
  __shared__ float redv[2][8];
  __shared__ int   redi[2][8];
  __shared__ int   pivseq[NN];
  __shared__ int   actlist[NN];
  __shared__ unsigned char pickedsh[NN];
  __shared__ int   nact;

  const int ls = blockIdx.x;
  float* __restrict__ A = Aall + (size_t)ls*NN*NN;
  const int t = threadIdx.x;
  const int lane = t & 63, wid = t >> 6;
  bool picked = false;
  if (t < NN) pickedsh[t] = 0;

  for (int I = 0; I < NPAN; ++I){
    const int col0 = I*PW;
    const int W = NN - col0 - PW;
    if (t == 0) nact = 0;
    __syncthreads();

    for (int e = t; e < NN*PW; e += 512){
      int r = e >> 5, c = e & 31;
      panel[r][c] = A[(size_t)r*NN + col0 + c];
    }
    __syncthreads();

    {
      float v = -1.0f; int vi = 0;
      if (t < NN && !picked){ v = fabsf(panel[t][0]); vi = t; }
      #pragma unroll
      for (int off = 32; off > 0; off >>= 1){
        float ov = __shfl_down(v, off); int oi = __shfl_down(vi, off);
        if (ov > v){ v = ov; vi = oi; }
      }
      if (lane == 0){ redv[0][wid] = v; redi[0][wid] = vi; }
    }
    __syncthreads();

    for (int c = 0; c < PW; ++c){
      const int par = c & 1;
      float bv = redv[par][0]; int p = redi[par][0];
      #pragma unroll
      for (int w = 1; w < 8; ++w)
        if (redv[par][w] > bv){ bv = redv[par][w]; p = redi[par][w]; }
      if (t == p){ picked = true; pickedsh[t] = 1; pivseq[col0+c] = t; }

      float nv = -1.0f; int ni = t;
      if (t < NN && !picked){
        const float rdia = 1.0f / panel[p][c];
        float m = panel[t][c] * rdia;
        panel[t][c] = m;
        float nxt = -1.0f;
        #pragma unroll
        for (int j = 0; j < PW; ++j){
          if (j > c){
            float u = panel[t][j] - m * panel[p][j];
            panel[t][j] = u;
            if (j == c+1) nxt = fabsf(u);
          }
        }
        nv = nxt;
      }
      #pragma unroll
      for (int off = 32; off > 0; off >>= 1){
        float ov = __shfl_down(nv, off); int oi = __shfl_down(ni, off);
        if (ov > nv){ nv = ov; ni = oi; }
      }
      if (lane == 0){ redv[par^1][wid] = nv; redi[par^1][wid] = ni; }
      __syncthreads();
    }

    if (t >= 256){
      const int jj = t - 256;
      if (jj < W){
        const int j = col0 + PW + jj;
        float u[PW];
        #pragma unroll
        for (int c = 0; c < PW; ++c) u[c] = A[(size_t)pivseq[col0+c]*NN + j];
        #pragma unroll
        for (int c = 0; c < PW; ++c){
          const int pc = pivseq[col0+c];
          float sv = u[c];
          #pragma unroll
          for (int k2 = 0; k2 < PW; ++k2)
            if (k2 < c) sv -= panel[pc][k2] * u[k2];
          u[c] = sv;
          urow[c][jj] = sv;
          A[(size_t)pc*NN + j] = sv;
        }
      }
    } else if (t < PW){
      const int cth = t;
      for (int r = cth; r < PW; ++r){
        float sv = (r == cth) ? 1.0f : 0.0f;
        const int pr = pivseq[col0+r];
        for (int k2 = cth; k2 < r; ++k2) sv -= panel[pr][k2] * linv[k2][cth];
        linv[r][cth] = sv;
      }
    } else if (t >= 64 && t < 64+PW){
      const int cth = t - 64;
      for (int r = cth; r >= 0; --r){
        float sv = (r == cth) ? 1.0f : 0.0f;
        const int pr = pivseq[col0+r];
        for (int k2 = r+1; k2 <= cth; ++k2) sv -= panel[pr][k2] * uinv[k2][cth];
        uinv[r][cth] = sv / panel[pr][r];
      }
    } else if (t >= 128 && t < 192){
      #pragma unroll
      for (int q = 0; q < 4; ++q){
        int r = (t-128)*4 + q;
        if (!pickedsh[r]){ int pos = atomicAdd(&nact, 1); actlist[pos] = r; }
      }
    }
    __syncthreads();

    for (int e = t; e < PW*PW; e += 512){
      int r = e >> 5, c2 = e & 31;
      A[(size_t)pivseq[col0+r]*NN + col0 + c2] = (r > c2) ? linv[r][c2] : uinv[r][c2];
    }
    for (int e = t; e < NN*PW; e += 512){
      int r = e >> 5, c2 = e & 31;
      if (!pickedsh[r]) A[(size_t)r*NN + col0 + c2] = panel[r][c2];
    }

    // ---- trailing update: active rows -= L21 * U12 (float4, 1 pass over cols) ----
    if (W > 0){
      for (int i0 = wid*2; i0 < W; i0 += 16){
        const int r0 = actlist[i0];
        const int r1 = actlist[i0+1];          // W is even: pair always valid
        float4* R0 = (float4*)(A + (size_t)r0*NN + col0 + PW);
        float4* R1 = (float4*)(A + (size_t)r1*NN + col0 + PW);
        if (lane*4 < W){
          float4 a0 = R0[lane];
          float4 a1 = R1[lane];
          #pragma unroll
          for (int c = 0; c < PW; ++c){
            float4 u4 = *(const float4*)&urow[c][lane*4];
            float p0 = panel[r0][c], p1 = panel[r1][c];
            a0.x -= p0*u4.x; a0.y -= p0*u4.y; a0.z -= p0*u4.z; a0.w -= p0*u4.w;
            a1.x -= p1*u4.x; a1.y -= p1*u4.y; a1.z -= p1*u4.z; a1.w -= p1*u4.w;
          }
          R0[lane] = a0;
          R1[lane] = a1;
        }
      }
    }
  }
  __syncthreads();
  if (t < NN) permAll[ls*NN + t] = pivseq[t];
}

// ---------------------------------------------------------------------------
// Kernel 3: blocked triangular solves + epilogue for ONE 64-col RHS chunk.
// grid = cs*4, XCD-swizzled so each XCD hosts 16 COMPLETE systems (streams
// fit its 4 MB L2 and are shared by the 4 sibling blocks).
// Rank-32 updates: 2 rows/wave-iteration, 16 independent float4 loads.
// ---------------------------------------------------------------------------
__global__ __launch_bounds__(512, 4) void solve_epi_kernel(
    const float* __restrict__ Aall, const int* __restrict__ permAll,
    const float* __restrict__ rowsum,
    const float* __restrict__ C, const float* __restrict__ val,
    const int* __restrict__ bad, const float* __restrict__ rm,
    float* __restrict__ out, int s0)
{
  __shared__ float tile[NN][64];      // 64 KiB
  __shared__ float dblk[PW][PW+1];
  __shared__ float ep[4][8][64];
  __shared__ int   perm[NN];

  int ls, c0;
  {
    const int g = blockIdx.x;
    if ((gridDim.x & 31) == 0){       // cs % 8 == 0: XCD co-location swizzle
      const int xcd = g & 7, idx = g >> 3;
      ls = xcd + 8*(idx >> 2);
      c0 = (idx & 3) * 64;
    } else {
      ls = g >> 2;
      c0 = (g & 3) * 64;
    }
  }
  const int s  = s0 + ls;
  const int k  = s >> 7, b = s & 127;
  const float* __restrict__ A = Aall + (size_t)ls*NN*NN;
  const float* __restrict__ rs = rowsum + ls*NN;
  const int t = threadIdx.x;
  const int lane = t & 63, wid = t >> 6;
  const float sk = sigmoidf_(rm[k]);

  if (t < NN) perm[t] = permAll[ls*NN + t];
  __syncthreads();

  // ---- build permuted RHS chunk on the fly ----
  for (int e = t; e < NN*64; e += 512){
    int i = e >> 6, c = e & 63;
    int pi = perm[i];
    float cb = C[((size_t)b*NN + pi)*(NN+PP) + NN + c0 + c];
    float xb = sk * cb;
    float bf = (1.0f + xb) * expf(-xb);
    if (bad[b*NN + pi]) bf = 0.0f;
    tile[i][c] = bf;
  }
  __syncthreads();

  // ---- forward: y = Linv-chain applied to Pb ----
  for (int J = 0; J < NPAN; ++J){
    const int j0 = J*PW;
    for (int e = t; e < PW*PW; e += 512){
      int r = e >> 5, c = e & 31;
      dblk[r][c] = A[(size_t)perm[j0+r]*NN + j0 + c];
    }
    __syncthreads();
    const int r0 = wid*4;
    float y0 = tile[j0+r0+0][lane];
    float y1 = tile[j0+r0+1][lane];
    float y2 = tile[j0+r0+2][lane];
    float y3 = tile[j0+r0+3][lane];
    for (int kk = 0; kk < r0; ++kk){
      float xk = tile[j0+kk][lane];
      y0 += dblk[r0+0][kk]*xk;
      y1 += dblk[r0+1][kk]*xk;
      y2 += dblk[r0+2][kk]*xk;
      y3 += dblk[r0+3][kk]*xk;
    }
    {
      float x0 = tile[j0+r0][lane], x1 = tile[j0+r0+1][lane], x2 = tile[j0+r0+2][lane];
      y1 += dblk[r0+1][r0]*x0;
      y2 += dblk[r0+2][r0]*x0 + dblk[r0+2][r0+1]*x1;
      y3 += dblk[r0+3][r0]*x0 + dblk[r0+3][r0+1]*x1 + dblk[r0+3][r0+2]*x2;
    }
    __syncthreads();
    tile[j0+r0+0][lane]=y0; tile[j0+r0+1][lane]=y1;
    tile[j0+r0+2][lane]=y2; tile[j0+r0+3][lane]=y3;
    __syncthreads();
    if (j0 + PW < NN){
      float x[PW];
      #pragma unroll
      for (int kk = 0; kk < PW; ++kk) x[kk] = tile[j0+kk][lane];
      const int nbelow = NN - j0 - PW;          // multiple of 32 -> even
      for (int i0 = wid*2; i0 < nbelow; i0 += 16){
        const int ia = j0 + PW + i0, ib = ia + 1;
        const float4* __restrict__ Ar0 = (const float4*)(A + (size_t)perm[ia]*NN + j0);
        const float4* __restrict__ Ar1 = (const float4*)(A + (size_t)perm[ib]*NN + j0);
        float acc0 = tile[ia][lane];
        float acc1 = tile[ib][lane];
        #pragma unroll
        for (int q = 0; q < 8; ++q){
          float4 a4 = Ar0[q], b4 = Ar1[q];
          acc0 -= a4.x*x[q*4+0] + a4.y*x[q*4+1] + a4.z*x[q*4+2] + a4.w*x[q*4+3];
          acc1 -= b4.x*x[q*4+0] + b4.y*x[q*4+1] + b4.z*x[q*4+2] + b4.w*x[q*4+3];
        }
        tile[ia][lane] = acc0;
        tile[ib][lane] = acc1;
      }
    }
    __syncthreads();
  }

  // ---- backward: d = Uinv-chain applied to y ----
  for (int J = NPAN-1; J >= 0; --J){
    const int j0 = J*PW;
    for (int e = t; e < PW*PW; e += 512){
      int r = e >> 5, c = e & 31;
      dblk[r][c] = A[(size_t)perm[j0+r]*NN + j0 + c];
    }
    __syncthreads();
    const int r0 = wid*4;
    float y0=0.f, y1=0.f, y2=0.f, y3=0.f;
    for (int kk = r0+4; kk < PW; ++kk){
      float xk = tile[j0+kk][lane];
      y0 += dblk[r0+0][kk]*xk;
      y1 += dblk[r0+1][kk]*xk;
      y2 += dblk[r0+2][kk]*xk;
      y3 += dblk[r0+3][kk]*xk;
    }
    {
      float x0 = tile[j0+r0][lane], x1 = tile[j0+r0+1][lane];
      float x2 = tile[j0+r0+2][lane], x3 = tile[j0+r0+3][lane];
      y0 += dblk[r0][r0]*x0 + dblk[r0][r0+1]*x1 + dblk[r0][r0+2]*x2 + dblk[r0][r0+3]*x3;
      y1 += dblk[r0+1][r0+1]*x1 + dblk[r0+1][r0+2]*x2 + dblk[r0+1][r0+3]*x3;
      y2 += dblk[r0+2][r0+2]*x2 + dblk[r0+2][r0+3]*x3;
      y3 += dblk[r0+3][r0+3]*x3;
    }
    __syncthreads();
    tile[j0+r0+0][lane]=y0; tile[j0+r0+1][lane]=y1;
    tile[j0+r0+2][lane]=y2; tile[j0+r0+3][lane]=y3;
    __syncthreads();
    if (j0 > 0){
      float x[PW];
      #pragma unroll
      for (int kk = 0; kk < PW; ++kk) x[kk] = tile[j0+kk][lane];
      for (int i0 = wid*2; i0 < j0; i0 += 16){   // j0 multiple of 32 -> even
        const int ia = i0, ib = i0 + 1;
        const float4* __restrict__ Ar0 = (const float4*)(A + (size_t)perm[ia]*NN + j0);
        const float4* __restrict__ Ar1 = (const float4*)(A + (size_t)perm[ib]*NN + j0);
        float acc0 = tile[ia][lane];
        float acc1 = tile[ib][lane];
        #pragma unroll
        for (int q = 0; q < 8; ++q){
          float4 a4 = Ar0[q], b4 = Ar1[q];
          acc0 -= a4.x*x[q*4+0] + a4.y*x[q*4+1] + a4.z*x[q*4+2] + a4.w*x[q*4+3];
          acc1 -= b4.x*x[q*4+0] + b4.y*x[q*4+1] + b4.z*x[q*4+2] + b4.w*x[q*4+3];
        }
        tile[ia][lane] = acc0;
        tile[ib][lane] = acc1;
      }
    }
    __syncthreads();
  }

  // ---- epilogue: 8-wave partial column reductions + combine ----
  {
    const int p = c0 + lane;
    float sdv=0.f, sabs=0.f, s1v=0.f, s1=0.f;
    for (int j = wid*32; j < wid*32 + 32; ++j){
      float d = tile[j][lane];
      float v = val[(b*NN + j)*KK + k];
      if (v != v) v = 0.0f;
      float cb = C[((size_t)b*NN + j)*(NN+PP) + NN + p];
      float xb = sk*cb;
      float bo = (1.0f+xb)*expf(-xb);
      if (bad[b*NN + j]) bo = 0.0f;
      float d1 = bo / rs[j];
      sdv += d*v; sabs += fabsf(d); s1v += d1*v; s1 += d1;
    }
    ep[0][wid][lane]=sdv; ep[1][wid][lane]=sabs; ep[2][wid][lane]=s1v; ep[3][wid][lane]=s1;
  }
  __syncthreads();
  if (t < 64){
    float sdv=0.f, sabs=0.f, s1v=0.f, s1=0.f;
    #pragma unroll
    for (int w = 0; w < 8; ++w){
      sdv += ep[0][w][lane]; sabs += ep[1][w][lane];
      s1v += ep[2][w][lane]; s1  += ep[3][w][lane];
    }
    float wg    = fminf(fmaxf((sabs - 1.0f)*2.0f, 0.0f), 1.0f);
    float denom = fmaxf(s1, 1.0f);
    out[((size_t)b*PP + c0 + lane)*KK + k] = (1.0f - wg)*sdv + (wg/denom)*s1v;
  }
}

// ---------------------------------------------------------------------------
extern "C" void kernel_launch(void* const* d_in, const int* in_sizes, int n_in,
                              void* d_out, int out_size, void* d_ws, size_t ws_size,
                              hipStream_t stream)
{
  (void)in_sizes; (void)n_in; (void)out_size;
  const float* C    = (const float*)d_in[0];
  const float* val  = (const float*)d_in[1];
  const float* rm   = (const float*)d_in[2];
  const float* epsp = (const float*)d_in[3];
  const int*   bad  = (const int*)d_in[4];
  float* out = (float*)d_out;

  // per-system workspace: A (NN*NN f32) + rowsum (NN f32) + perm (NN i32)
  const size_t per_sys = (size_t)NN*NN*4 + (size_t)NN*4 + (size_t)NN*4;
  int chunk = (int)(ws_size / per_sys);
  if (chunk < 1)    chunk = 1;
  if (chunk > NSYS) chunk = NSYS;

  float* ws     = (float*)d_ws;
  float* A      = ws;
  float* rowsum = A + (size_t)chunk*NN*NN;
  int*   perm   = (int*)(rowsum + (size_t)chunk*NN);

  for (int s0 = 0; s0 < NSYS; s0 += chunk){
    int cs = (NSYS - s0 < chunk) ? (NSYS - s0) : chunk;
    build_kernel<<<cs*NN, 256, 0, stream>>>(C, rm, epsp, bad, A, rowsum, s0);
    lu_kernel<<<cs, 512, 0, stream>>>(A, perm);
    solve_epi_kernel<<<cs*4, 512, 0, stream>>>(A, perm, rowsum, C, val, bad, rm, out, s0);
  }
}